// Round 2
// baseline (688.810 us; speedup 1.0000x reference)
//
#include <hip/hip_runtime.h>
#include <stdint.h>

typedef unsigned short u16;
typedef short short8 __attribute__((ext_vector_type(8)));
typedef float f32x4 __attribute__((ext_vector_type(4)));

#define MFMA16(a,b,c) __builtin_amdgcn_mfma_f32_16x16x32_bf16((a),(b),(c),0,0,0)

__device__ __forceinline__ u16 f2bf(float f) {
  union { float f; unsigned u; } v; v.f = f;
  unsigned r = v.u + 0x7FFFu + ((v.u >> 16) & 1u);
  return (u16)(r >> 16);
}

__device__ __forceinline__ void async16(u16* lds, const u16* g) {
  __builtin_amdgcn_global_load_lds(
      (const __attribute__((address_space(1))) void*)g,
      (__attribute__((address_space(3))) void*)lds, 16, 0, 0);
}

// ---------------- kernel 1: convert x (fp32 -> bf16) ----------------
__global__ __launch_bounds__(256) void k_conv_x(const float* __restrict__ x,
                                                u16* __restrict__ xb, int n8) {
  int stride = gridDim.x * blockDim.x;
  for (int i = blockIdx.x * blockDim.x + threadIdx.x; i < n8; i += stride) {
    const float4* p = (const float4*)(x + (size_t)i * 8);
    float4 a = p[0], b = p[1];
    union { u16 h[8]; uint4 v; } o;
    o.h[0] = f2bf(a.x); o.h[1] = f2bf(a.y); o.h[2] = f2bf(a.z); o.h[3] = f2bf(a.w);
    o.h[4] = f2bf(b.x); o.h[5] = f2bf(b.y); o.h[6] = f2bf(b.z); o.h[7] = f2bf(b.w);
    *(uint4*)(xb + (size_t)i * 8) = o.v;
  }
}

// ---------------- kernel 1b: convert weights ----------------
__global__ __launch_bounds__(256) void k_conv_w(const float* __restrict__ wb,
                                                const float* __restrict__ wdown,
                                                const float* __restrict__ wup,
                                                u16* __restrict__ wbb,
                                                u16* __restrict__ wdownb,
                                                u16* __restrict__ wupb) {
  int idx = blockIdx.x * blockDim.x + threadIdx.x;
  int total = gridDim.x * blockDim.x;
  for (int i = idx; i < 1024 * 1024 / 8; i += total) {
    const float4* p = (const float4*)(wb + (size_t)i * 8);
    float4 a = p[0], b = p[1];
    union { u16 h[8]; uint4 v; } o;
    o.h[0] = f2bf(a.x); o.h[1] = f2bf(a.y); o.h[2] = f2bf(a.z); o.h[3] = f2bf(a.w);
    o.h[4] = f2bf(b.x); o.h[5] = f2bf(b.y); o.h[6] = f2bf(b.z); o.h[7] = f2bf(b.w);
    *(uint4*)(wbb + (size_t)i * 8) = o.v;
  }
  for (int i = idx; i < 32 * 1024; i += total) wdownb[i] = f2bf(wdown[i]);
  // fold SCALING=4 into Wup (the ONLY place SCALING is applied)
  for (int i = idx; i < 1024 * 32; i += total) wupb[i] = f2bf(wup[i] * 4.0f);
}

// ---------------- kernel 2: red = x @ Wdown.T  (M=65536,N=32,K=1024) ----------------
__global__ __launch_bounds__(256) void k_red(const u16* __restrict__ xb,
                                             const u16* __restrict__ wdownb,
                                             float* __restrict__ red) {
  __shared__ u16 As[128 * 64];  // 16KB, [row][64] bf16
  int tid = threadIdx.x;
  int lane = tid & 63, wid = tid >> 6;
  int m0 = blockIdx.x * 128;
  f32x4 acc[2][2] = {};
  int srow = wid * 32 + (lane >> 3);
  int scol = (lane & 7) * 8;
  const u16* gA = xb + (size_t)(m0 + srow) * 1024 + scol;
  u16* lA = &As[(wid * 32) * 64];
  for (int k0 = 0; k0 < 1024; k0 += 64) {
    if (k0) __syncthreads();
    async16(lA,           gA + k0);
    async16(lA + 8 * 64,  gA + k0 + (size_t)8 * 1024);
    async16(lA + 16 * 64, gA + k0 + (size_t)16 * 1024);
    async16(lA + 24 * 64, gA + k0 + (size_t)24 * 1024);
    __syncthreads();
#pragma unroll
    for (int ks = 0; ks < 2; ++ks) {
      short8 a[2], b[2];
#pragma unroll
      for (int mi = 0; mi < 2; ++mi)
        a[mi] = *(const short8*)&As[(wid * 32 + mi * 16 + (lane & 15)) * 64 +
                                    ks * 32 + (lane >> 4) * 8];
#pragma unroll
      for (int ni = 0; ni < 2; ++ni)
        b[ni] = *(const short8*)(wdownb + (size_t)(ni * 16 + (lane & 15)) * 1024 +
                                 k0 + ks * 32 + (lane >> 4) * 8);
#pragma unroll
      for (int mi = 0; mi < 2; ++mi)
#pragma unroll
        for (int ni = 0; ni < 2; ++ni)
          acc[mi][ni] = MFMA16(a[mi], b[ni], acc[mi][ni]);
    }
  }
#pragma unroll
  for (int mi = 0; mi < 2; ++mi)
#pragma unroll
    for (int ni = 0; ni < 2; ++ni)
#pragma unroll
      for (int r = 0; r < 4; ++r) {
        int row = m0 + wid * 32 + mi * 16 + (lane >> 4) * 4 + r;
        int col = ni * 16 + (lane & 15);
        red[(size_t)row * 32 + col] = acc[mi][ni][r];
      }
}

// ---------------- kernel 3: SSM scan ----------------
__global__ __launch_bounds__(256) void k_ssm(const float* __restrict__ red,
                                             u16* __restrict__ oseq,
                                             const float* __restrict__ A_log,
                                             const float* __restrict__ Dp,
                                             const float* __restrict__ Wxp,
                                             const float* __restrict__ bxp,
                                             const float* __restrict__ Wout,
                                             const float* __restrict__ bout) {
  __shared__ float sx[8][32], sbc[8][32], sy[8][32];
  int tid = threadIdx.x;
  int g = tid >> 5, r = tid & 31;
  int n = blockIdx.x * 8 + g;
  int b = n >> 10, p = n & 1023;
  float wxA[32], wxB[32], wo[32];
#pragma unroll
  for (int k = 0; k < 32; ++k) {
    wxA[k] = Wxp[r * 32 + k];
    wxB[k] = Wxp[(32 + r) * 32 + k];
    wo[k]  = Wout[r * 32 + k];
  }
  float Ar[16];
#pragma unroll
  for (int s = 0; s < 16; ++s) Ar[s] = -__expf(A_log[r * 16 + s]);
  float dpr = Dp[r];
  float bx1 = bxp[r], bx2 = bxp[32 + r], bo = bout[r];
  float h[16];
#pragma unroll
  for (int s = 0; s < 16; ++s) h[s] = 0.f;
  for (int t = 0; t < 8; ++t) {
    size_t rowt = (size_t)(b * 8 + t) * 1024 + p;
    float xr = red[rowt * 32 + r];
    sx[g][r] = xr;
    __syncthreads();  // S1
    float p1 = bx1, p2 = bx2;
#pragma unroll
    for (int k = 0; k < 32; ++k) {
      float xv = sx[g][k];
      p1 = fmaf(wxA[k], xv, p1);
      p2 = fmaf(wxB[k], xv, p2);
    }
    float dlt = (p1 > 20.f) ? p1 : log1pf(__expf(p1));  // softplus
    sbc[g][r] = p2;
    __syncthreads();  // S2
    float yr = dpr * xr;
#pragma unroll
    for (int s = 0; s < 16; ++s) {
      float Bm = sbc[g][s];
      float Cm = sbc[g][16 + s];
      float ab = __expf(dlt * Ar[s]);
      h[s] = fmaf(ab, h[s], dlt * Bm * xr);
      yr = fmaf(h[s], Cm, yr);
    }
    sy[g][r] = yr;
    __syncthreads();  // S3
    float ov = bo;
#pragma unroll
    for (int k = 0; k < 32; ++k) ov = fmaf(wo[k], sy[g][k], ov);
    oseq[rowt * 32 + r] = f2bf(ov);  // SCALING folded into wupb, NOT here
  }
}

// ---------------- kernel 4: fused GEMM  out = x@Wb.T + bb + oseq@(4*Wup).T ----------------
__global__ __launch_bounds__(256) void k_gemm(const u16* __restrict__ xb,
                                              const u16* __restrict__ wbb,
                                              const u16* __restrict__ oseq,
                                              const u16* __restrict__ wupb,
                                              const float* __restrict__ bb,
                                              float* __restrict__ out) {
  __shared__ u16 As[128 * 32];  // 8KB
  __shared__ u16 Bs[128 * 32];  // 8KB
  int bid = blockIdx.x;
  int sw = (bid & 7) * 512 + (bid >> 3);  // XCD swizzle (4096 % 8 == 0, bijective)
  int mt = sw >> 3, nt = sw & 7;
  int m0 = mt * 128, n0 = nt * 128;
  int tid = threadIdx.x, lane = tid & 63, wid = tid >> 6;
  int wr = (wid >> 1) * 64, wc = (wid & 1) * 64;
  f32x4 acc[4][4] = {};
  int srow = wid * 32 + (lane >> 2);
  int scol = (lane & 3) * 8;
  const u16* gA = xb  + (size_t)(m0 + srow) * 1024 + scol;
  const u16* gB = wbb + (size_t)(n0 + srow) * 1024 + scol;
  u16* lA = &As[wid * 32 * 32];
  u16* lB = &Bs[wid * 32 * 32];
  for (int k0 = 0; k0 < 1024; k0 += 32) {
    if (k0) __syncthreads();
    async16(lA,           gA + k0);
    async16(lA + 16 * 32, gA + k0 + (size_t)16 * 1024);
    async16(lB,           gB + k0);
    async16(lB + 16 * 32, gB + k0 + (size_t)16 * 1024);
    __syncthreads();
    short8 a[4], b[4];
#pragma unroll
    for (int mi = 0; mi < 4; ++mi)
      a[mi] = *(const short8*)&As[(wr + mi * 16 + (lane & 15)) * 32 + (lane >> 4) * 8];
#pragma unroll
    for (int ni = 0; ni < 4; ++ni)
      b[ni] = *(const short8*)&Bs[(wc + ni * 16 + (lane & 15)) * 32 + (lane >> 4) * 8];
#pragma unroll
    for (int mi = 0; mi < 4; ++mi)
#pragma unroll
      for (int ni = 0; ni < 4; ++ni)
        acc[mi][ni] = MFMA16(a[mi], b[ni], acc[mi][ni]);
  }
  // epilogue: delta = oseq @ (4*Wup).T via one K=32 MFMA per fragment
  short8 ae[4], be[4];
#pragma unroll
  for (int mi = 0; mi < 4; ++mi) {
    int row = m0 + wr + mi * 16 + (lane & 15);
    ae[mi] = *(const short8*)(oseq + (size_t)row * 32 + (lane >> 4) * 8);
  }
#pragma unroll
  for (int ni = 0; ni < 4; ++ni) {
    int col = n0 + wc + ni * 16 + (lane & 15);
    be[ni] = *(const short8*)(wupb + (size_t)col * 32 + (lane >> 4) * 8);
  }
#pragma unroll
  for (int mi = 0; mi < 4; ++mi)
#pragma unroll
    for (int ni = 0; ni < 4; ++ni)
      acc[mi][ni] = MFMA16(ae[mi], be[ni], acc[mi][ni]);
  float bias[4];
#pragma unroll
  for (int ni = 0; ni < 4; ++ni) bias[ni] = bb[n0 + wc + ni * 16 + (lane & 15)];
#pragma unroll
  for (int mi = 0; mi < 4; ++mi)
#pragma unroll
    for (int ni = 0; ni < 4; ++ni) {
      int col = n0 + wc + ni * 16 + (lane & 15);
#pragma unroll
      for (int r = 0; r < 4; ++r) {
        int row = m0 + wr + mi * 16 + (lane >> 4) * 4 + r;
        out[(size_t)row * 1024 + col] = acc[mi][ni][r] + bias[ni];
      }
    }
}

extern "C" void kernel_launch(void* const* d_in, const int* in_sizes, int n_in,
                              void* d_out, int out_size, void* d_ws, size_t ws_size,
                              hipStream_t stream) {
  const float* x     = (const float*)d_in[0];
  const float* Wb    = (const float*)d_in[1];
  const float* bb    = (const float*)d_in[2];
  const float* Wdown = (const float*)d_in[3];
  const float* Wup   = (const float*)d_in[4];
  const float* A_log = (const float*)d_in[5];
  const float* Dp    = (const float*)d_in[6];
  const float* Wxp   = (const float*)d_in[7];
  const float* bxp   = (const float*)d_in[8];
  const float* Wout  = (const float*)d_in[9];
  const float* bout  = (const float*)d_in[10];

  char* ws = (char*)d_ws;
  u16*   xb     = (u16*)(ws);                      // 134217728 B
  u16*   wbb    = (u16*)(ws + 134217728);          // 2097152 B
  u16*   wdownb = (u16*)(ws + 136314880);          // 65536 B
  u16*   wupb   = (u16*)(ws + 136380416);          // 65536 B
  float* red    = (float*)(ws + 136445952);        // 8388608 B
  u16*   oseq   = (u16*)(ws + 144834560);          // 4194304 B
  float* out = (float*)d_out;

  hipLaunchKernelGGL(k_conv_x, dim3(8192), dim3(256), 0, stream, x, xb, 64 * 1024 * 1024 / 8);
  hipLaunchKernelGGL(k_conv_w, dim3(512), dim3(256), 0, stream, Wb, Wdown, Wup, wbb, wdownb, wupb);
  hipLaunchKernelGGL(k_red, dim3(512), dim3(256), 0, stream, xb, wdownb, red);
  hipLaunchKernelGGL(k_ssm, dim3(1024), dim3(256), 0, stream, red, oseq, A_log, Dp, Wxp, bxp, Wout, bout);
  hipLaunchKernelGGL(k_gemm, dim3(4096), dim3(256), 0, stream, xb, wbb, oseq, wupb, bb, out);
}

// Round 3
// 686.698 us; speedup vs baseline: 1.0031x; 1.0031x over previous
//
#include <hip/hip_runtime.h>
#include <stdint.h>

typedef unsigned short u16;
typedef short short8 __attribute__((ext_vector_type(8)));
typedef float f32x4 __attribute__((ext_vector_type(4)));

#define MFMA16(a,b,c) __builtin_amdgcn_mfma_f32_16x16x32_bf16((a),(b),(c),0,0,0)

__device__ __forceinline__ u16 f2bf(float f) {
  union { float f; unsigned u; } v; v.f = f;
  unsigned r = v.u + 0x7FFFu + ((v.u >> 16) & 1u);
  return (u16)(r >> 16);
}

__device__ __forceinline__ void async16(u16* lds, const u16* g) {
  __builtin_amdgcn_global_load_lds(
      (const __attribute__((address_space(1))) void*)g,
      (__attribute__((address_space(3))) void*)lds, 16, 0, 0);
}

// ---------------- kernel 1: convert weights ----------------
__global__ __launch_bounds__(256) void k_conv_w(const float* __restrict__ wb,
                                                const float* __restrict__ wdown,
                                                const float* __restrict__ wup,
                                                u16* __restrict__ wbb,
                                                u16* __restrict__ wdownb,
                                                u16* __restrict__ wupb) {
  int idx = blockIdx.x * blockDim.x + threadIdx.x;
  int total = gridDim.x * blockDim.x;
  for (int i = idx; i < 1024 * 1024 / 8; i += total) {
    const float4* p = (const float4*)(wb + (size_t)i * 8);
    float4 a = p[0], b = p[1];
    union { u16 h[8]; uint4 v; } o;
    o.h[0] = f2bf(a.x); o.h[1] = f2bf(a.y); o.h[2] = f2bf(a.z); o.h[3] = f2bf(a.w);
    o.h[4] = f2bf(b.x); o.h[5] = f2bf(b.y); o.h[6] = f2bf(b.z); o.h[7] = f2bf(b.w);
    *(uint4*)(wbb + (size_t)i * 8) = o.v;
  }
  for (int i = idx; i < 32 * 1024; i += total) wdownb[i] = f2bf(wdown[i]);
  // fold SCALING=4 into Wup (the ONLY place SCALING is applied)
  for (int i = idx; i < 1024 * 32; i += total) wupb[i] = f2bf(wup[i] * 4.0f);
}

// ---------------- kernel 2: fused convert + reduce ----------------
// xb = bf16(x); red = x @ Wdown.T   (register-resident, no LDS, no barriers)
// Wave owns 16 rows. Lane loads exactly its MFMA A-fragment (row=lane&15,
// k=(lane>>4)*8+j) as fp32, converts, stores bf16, feeds MFMA directly.
__global__ __launch_bounds__(256) void k_prep(const float* __restrict__ x,
                                              const u16* __restrict__ wdownb,
                                              u16* __restrict__ xb,
                                              float* __restrict__ red) {
  int lane = threadIdx.x & 63, wid = threadIdx.x >> 6;
  int base = blockIdx.x * 64 + wid * 16;
  int row = base + (lane & 15);
  int q8 = (lane >> 4) * 8;
  const float* gx = x + (size_t)row * 1024 + q8;
  u16* gxb = xb + (size_t)row * 1024 + q8;
  const u16* wd0 = wdownb + (size_t)(lane & 15) * 1024 + q8;
  f32x4 acc0 = {}, acc1 = {};
#pragma unroll 4
  for (int k0 = 0; k0 < 1024; k0 += 32) {
    float4 a = *(const float4*)(gx + k0);
    float4 c = *(const float4*)(gx + k0 + 4);
    union { u16 h[8]; uint4 v; short8 s; } o;
    o.h[0] = f2bf(a.x); o.h[1] = f2bf(a.y); o.h[2] = f2bf(a.z); o.h[3] = f2bf(a.w);
    o.h[4] = f2bf(c.x); o.h[5] = f2bf(c.y); o.h[6] = f2bf(c.z); o.h[7] = f2bf(c.w);
    *(uint4*)(gxb + k0) = o.v;
    short8 b0 = *(const short8*)(wd0 + k0);
    short8 b1 = *(const short8*)(wd0 + k0 + 16 * 1024);
    acc0 = MFMA16(o.s, b0, acc0);
    acc1 = MFMA16(o.s, b1, acc1);
  }
  int orow = base + (lane >> 4) * 4;
#pragma unroll
  for (int rr = 0; rr < 4; ++rr) {
    red[(size_t)(orow + rr) * 32 + (lane & 15)] = acc0[rr];
    red[(size_t)(orow + rr) * 32 + 16 + (lane & 15)] = acc1[rr];
  }
}

// ---------------- kernel 3: SSM scan (wave-synchronous, no barriers) ----------------
// 2 sequences per wave (lane>>5), rank r = lane&31; 32-wide broadcasts via shfl.
__global__ __launch_bounds__(256) void k_ssm(const float* __restrict__ red,
                                             u16* __restrict__ oseq,
                                             const float* __restrict__ A_log,
                                             const float* __restrict__ Dp,
                                             const float* __restrict__ Wxp,
                                             const float* __restrict__ bxp,
                                             const float* __restrict__ Wout,
                                             const float* __restrict__ bout) {
  int lane = threadIdx.x & 63;
  int r = lane & 31;
  int hb = lane & 32;  // shfl half-base
  int gw = blockIdx.x * 4 + (threadIdx.x >> 6);
  int n = gw * 2 + (lane >> 5);
  int b = n >> 10, p = n & 1023;
  float wxA[32], wxB[32], wo[32];
#pragma unroll
  for (int k = 0; k < 32; ++k) {
    wxA[k] = Wxp[r * 32 + k];
    wxB[k] = Wxp[(32 + r) * 32 + k];
    wo[k]  = Wout[r * 32 + k];
  }
  float Ar[16];
#pragma unroll
  for (int s = 0; s < 16; ++s) Ar[s] = -__expf(A_log[r * 16 + s]);
  float dpr = Dp[r];
  float bx1 = bxp[r], bx2 = bxp[32 + r], bo = bout[r];
  float h[16];
#pragma unroll
  for (int s = 0; s < 16; ++s) h[s] = 0.f;
  for (int t = 0; t < 8; ++t) {
    size_t rowt = (size_t)(b * 8 + t) * 1024 + p;
    float xr = red[rowt * 32 + r];
    float p1 = bx1, p2 = bx2;
#pragma unroll
    for (int k = 0; k < 32; ++k) {
      float xv = __shfl(xr, hb + k);
      p1 = fmaf(wxA[k], xv, p1);
      p2 = fmaf(wxB[k], xv, p2);
    }
    float dlt = (p1 > 20.f) ? p1 : log1pf(__expf(p1));  // softplus
    float yr = dpr * xr;
#pragma unroll
    for (int s = 0; s < 16; ++s) {
      float Bm = __shfl(p2, hb + s);
      float Cm = __shfl(p2, hb + 16 + s);
      float ab = __expf(dlt * Ar[s]);
      h[s] = fmaf(ab, h[s], dlt * Bm * xr);
      yr = fmaf(h[s], Cm, yr);
    }
    float ov = bo;
#pragma unroll
    for (int k = 0; k < 32; ++k) ov = fmaf(wo[k], __shfl(yr, hb + k), ov);
    oseq[rowt * 32 + r] = f2bf(ov);  // SCALING folded into wupb, NOT here
  }
}

// ---------------- kernel 4: fused GEMM  out = x@Wb.T + bb + oseq@(4*Wup).T ----------------
__global__ __launch_bounds__(256) void k_gemm(const u16* __restrict__ xb,
                                              const u16* __restrict__ wbb,
                                              const u16* __restrict__ oseq,
                                              const u16* __restrict__ wupb,
                                              const float* __restrict__ bb,
                                              float* __restrict__ out) {
  __shared__ u16 As[128 * 32];  // 8KB
  __shared__ u16 Bs[128 * 32];  // 8KB
  int bid = blockIdx.x;
  int sw = (bid & 7) * 512 + (bid >> 3);  // XCD swizzle (4096 % 8 == 0, bijective)
  int mt = sw >> 3, nt = sw & 7;
  int m0 = mt * 128, n0 = nt * 128;
  int tid = threadIdx.x, lane = tid & 63, wid = tid >> 6;
  int wr = (wid >> 1) * 64, wc = (wid & 1) * 64;
  f32x4 acc[4][4] = {};
  int srow = wid * 32 + (lane >> 2);
  int scol = (lane & 3) * 8;
  const u16* gA = xb  + (size_t)(m0 + srow) * 1024 + scol;
  const u16* gB = wbb + (size_t)(n0 + srow) * 1024 + scol;
  u16* lA = &As[wid * 32 * 32];
  u16* lB = &Bs[wid * 32 * 32];
  for (int k0 = 0; k0 < 1024; k0 += 32) {
    if (k0) __syncthreads();
    async16(lA,           gA + k0);
    async16(lA + 16 * 32, gA + k0 + (size_t)16 * 1024);
    async16(lB,           gB + k0);
    async16(lB + 16 * 32, gB + k0 + (size_t)16 * 1024);
    __syncthreads();
    short8 a[4], b[4];
#pragma unroll
    for (int mi = 0; mi < 4; ++mi)
      a[mi] = *(const short8*)&As[(wr + mi * 16 + (lane & 15)) * 32 + (lane >> 4) * 8];
#pragma unroll
    for (int ni = 0; ni < 4; ++ni)
      b[ni] = *(const short8*)&Bs[(wc + ni * 16 + (lane & 15)) * 32 + (lane >> 4) * 8];
#pragma unroll
    for (int mi = 0; mi < 4; ++mi)
#pragma unroll
      for (int ni = 0; ni < 4; ++ni)
        acc[mi][ni] = MFMA16(a[mi], b[ni], acc[mi][ni]);
  }
  // epilogue: delta = oseq @ (4*Wup).T via one K=32 MFMA per fragment
  short8 ae[4], be[4];
#pragma unroll
  for (int mi = 0; mi < 4; ++mi) {
    int row = m0 + wr + mi * 16 + (lane & 15);
    ae[mi] = *(const short8*)(oseq + (size_t)row * 32 + (lane >> 4) * 8);
  }
#pragma unroll
  for (int ni = 0; ni < 4; ++ni) {
    int col = n0 + wc + ni * 16 + (lane & 15);
    be[ni] = *(const short8*)(wupb + (size_t)col * 32 + (lane >> 4) * 8);
  }
#pragma unroll
  for (int mi = 0; mi < 4; ++mi)
#pragma unroll
    for (int ni = 0; ni < 4; ++ni)
      acc[mi][ni] = MFMA16(ae[mi], be[ni], acc[mi][ni]);
  float bias[4];
#pragma unroll
  for (int ni = 0; ni < 4; ++ni) bias[ni] = bb[n0 + wc + ni * 16 + (lane & 15)];
#pragma unroll
  for (int mi = 0; mi < 4; ++mi)
#pragma unroll
    for (int ni = 0; ni < 4; ++ni) {
      int col = n0 + wc + ni * 16 + (lane & 15);
#pragma unroll
      for (int r = 0; r < 4; ++r) {
        int row = m0 + wr + mi * 16 + (lane >> 4) * 4 + r;
        out[(size_t)row * 1024 + col] = acc[mi][ni][r] + bias[ni];
      }
    }
}

extern "C" void kernel_launch(void* const* d_in, const int* in_sizes, int n_in,
                              void* d_out, int out_size, void* d_ws, size_t ws_size,
                              hipStream_t stream) {
  const float* x     = (const float*)d_in[0];
  const float* Wb    = (const float*)d_in[1];
  const float* bb    = (const float*)d_in[2];
  const float* Wdown = (const float*)d_in[3];
  const float* Wup   = (const float*)d_in[4];
  const float* A_log = (const float*)d_in[5];
  const float* Dp    = (const float*)d_in[6];
  const float* Wxp   = (const float*)d_in[7];
  const float* bxp   = (const float*)d_in[8];
  const float* Wout  = (const float*)d_in[9];
  const float* bout  = (const float*)d_in[10];

  char* ws = (char*)d_ws;
  u16*   xb     = (u16*)(ws);                      // 134217728 B
  u16*   wbb    = (u16*)(ws + 134217728);          // 2097152 B
  u16*   wdownb = (u16*)(ws + 136314880);          // 65536 B
  u16*   wupb   = (u16*)(ws + 136380416);          // 65536 B
  float* red    = (float*)(ws + 136445952);        // 8388608 B
  u16*   oseq   = (u16*)(ws + 144834560);          // 4194304 B
  float* out = (float*)d_out;

  hipLaunchKernelGGL(k_conv_w, dim3(512), dim3(256), 0, stream, Wb, Wdown, Wup, wbb, wdownb, wupb);
  hipLaunchKernelGGL(k_prep, dim3(1024), dim3(256), 0, stream, x, wdownb, xb, red);
  hipLaunchKernelGGL(k_ssm, dim3(1024), dim3(256), 0, stream, red, oseq, A_log, Dp, Wxp, bxp, Wout, bout);
  hipLaunchKernelGGL(k_gemm, dim3(4096), dim3(256), 0, stream, xb, wbb, oseq, wupb, bb, out);
}

// Round 5
// 660.380 us; speedup vs baseline: 1.0431x; 1.0399x over previous
//
#include <hip/hip_runtime.h>
#include <stdint.h>

typedef unsigned short u16;
typedef short short8 __attribute__((ext_vector_type(8)));
typedef float f32x4 __attribute__((ext_vector_type(4)));

#define MFMA16(a,b,c) __builtin_amdgcn_mfma_f32_16x16x32_bf16((a),(b),(c),0,0,0)

__device__ __forceinline__ u16 f2bf(float f) {
  union { float f; unsigned u; } v; v.f = f;
  unsigned r = v.u + 0x7FFFu + ((v.u >> 16) & 1u);
  return (u16)(r >> 16);
}

__device__ __forceinline__ void async16(u16* lds, const u16* g) {
  __builtin_amdgcn_global_load_lds(
      (const __attribute__((address_space(1))) void*)g,
      (__attribute__((address_space(3))) void*)lds, 16, 0, 0);
}

#define LGKM0 do { asm volatile("s_waitcnt lgkmcnt(0)" ::: "memory"); \
                   __builtin_amdgcn_sched_barrier(0); } while (0)
#define BARR  do { __builtin_amdgcn_s_barrier(); \
                   __builtin_amdgcn_sched_barrier(0); } while (0)

// ---------------- kernel 1: convert weights ----------------
__global__ __launch_bounds__(256) void k_conv_w(const float* __restrict__ wb,
                                                const float* __restrict__ wdown,
                                                const float* __restrict__ wup,
                                                u16* __restrict__ wbb,
                                                u16* __restrict__ wdownb,
                                                u16* __restrict__ wupb) {
  int idx = blockIdx.x * blockDim.x + threadIdx.x;
  int total = gridDim.x * blockDim.x;
  for (int i = idx; i < 1024 * 1024 / 8; i += total) {
    const float4* p = (const float4*)(wb + (size_t)i * 8);
    float4 a = p[0], b = p[1];
    union { u16 h[8]; uint4 v; } o;
    o.h[0] = f2bf(a.x); o.h[1] = f2bf(a.y); o.h[2] = f2bf(a.z); o.h[3] = f2bf(a.w);
    o.h[4] = f2bf(b.x); o.h[5] = f2bf(b.y); o.h[6] = f2bf(b.z); o.h[7] = f2bf(b.w);
    *(uint4*)(wbb + (size_t)i * 8) = o.v;
  }
  for (int i = idx; i < 32 * 1024; i += total) wdownb[i] = f2bf(wdown[i]);
  // fold SCALING=4 into Wup (the ONLY place SCALING is applied)
  for (int i = idx; i < 1024 * 32; i += total) wupb[i] = f2bf(wup[i] * 4.0f);
}

// ---------------- kernel 2: fused convert + reduce ----------------
__global__ __launch_bounds__(256) void k_prep(const float* __restrict__ x,
                                              const u16* __restrict__ wdownb,
                                              u16* __restrict__ xb,
                                              float* __restrict__ red) {
  int lane = threadIdx.x & 63, wid = threadIdx.x >> 6;
  int base = blockIdx.x * 64 + wid * 16;
  int row = base + (lane & 15);
  int q8 = (lane >> 4) * 8;
  const float* gx = x + (size_t)row * 1024 + q8;
  u16* gxb = xb + (size_t)row * 1024 + q8;
  const u16* wd0 = wdownb + (size_t)(lane & 15) * 1024 + q8;
  f32x4 acc0 = {}, acc1 = {};
#pragma unroll 4
  for (int k0 = 0; k0 < 1024; k0 += 32) {
    float4 a = *(const float4*)(gx + k0);
    float4 c = *(const float4*)(gx + k0 + 4);
    union { u16 h[8]; uint4 v; short8 s; } o;
    o.h[0] = f2bf(a.x); o.h[1] = f2bf(a.y); o.h[2] = f2bf(a.z); o.h[3] = f2bf(a.w);
    o.h[4] = f2bf(c.x); o.h[5] = f2bf(c.y); o.h[6] = f2bf(c.z); o.h[7] = f2bf(c.w);
    *(uint4*)(gxb + k0) = o.v;
    short8 b0 = *(const short8*)(wd0 + k0);
    short8 b1 = *(const short8*)(wd0 + k0 + 16 * 1024);
    acc0 = MFMA16(o.s, b0, acc0);
    acc1 = MFMA16(o.s, b1, acc1);
  }
  int orow = base + (lane >> 4) * 4;
#pragma unroll
  for (int rr = 0; rr < 4; ++rr) {
    red[(size_t)(orow + rr) * 32 + (lane & 15)] = acc0[rr];
    red[(size_t)(orow + rr) * 32 + 16 + (lane & 15)] = acc1[rr];
  }
}

// ---------------- kernel 3: SSM scan (wave-synchronous) ----------------
__global__ __launch_bounds__(256) void k_ssm(const float* __restrict__ red,
                                             u16* __restrict__ oseq,
                                             const float* __restrict__ A_log,
                                             const float* __restrict__ Dp,
                                             const float* __restrict__ Wxp,
                                             const float* __restrict__ bxp,
                                             const float* __restrict__ Wout,
                                             const float* __restrict__ bout) {
  int lane = threadIdx.x & 63;
  int r = lane & 31;
  int hb = lane & 32;
  int gw = blockIdx.x * 4 + (threadIdx.x >> 6);
  int n = gw * 2 + (lane >> 5);
  int b = n >> 10, p = n & 1023;
  float wxA[32], wxB[32], wo[32];
#pragma unroll
  for (int k = 0; k < 32; ++k) {
    wxA[k] = Wxp[r * 32 + k];
    wxB[k] = Wxp[(32 + r) * 32 + k];
    wo[k]  = Wout[r * 32 + k];
  }
  float Ar[16];
#pragma unroll
  for (int s = 0; s < 16; ++s) Ar[s] = -__expf(A_log[r * 16 + s]);
  float dpr = Dp[r];
  float bx1 = bxp[r], bx2 = bxp[32 + r], bo = bout[r];
  float h[16];
#pragma unroll
  for (int s = 0; s < 16; ++s) h[s] = 0.f;
  for (int t = 0; t < 8; ++t) {
    size_t rowt = (size_t)(b * 8 + t) * 1024 + p;
    float xr = red[rowt * 32 + r];
    float p1 = bx1, p2 = bx2;
#pragma unroll
    for (int k = 0; k < 32; ++k) {
      float xv = __shfl(xr, hb + k);
      p1 = fmaf(wxA[k], xv, p1);
      p2 = fmaf(wxB[k], xv, p2);
    }
    float dlt = (p1 > 20.f) ? p1 : log1pf(__expf(p1));
    float yr = dpr * xr;
#pragma unroll
    for (int s = 0; s < 16; ++s) {
      float Bm = __shfl(p2, hb + s);
      float Cm = __shfl(p2, hb + 16 + s);
      float ab = __expf(dlt * Ar[s]);
      h[s] = fmaf(ab, h[s], dlt * Bm * xr);
      yr = fmaf(h[s], Cm, yr);
    }
    float ov = bo;
#pragma unroll
    for (int k = 0; k < 32; ++k) ov = fmaf(wo[k], __shfl(yr, hb + k), ov);
    oseq[rowt * 32 + r] = f2bf(ov);
  }
}

// ---------------- kernel 4: 256x256 BK=64 counted-vmcnt pipelined GEMM ----------------
// out = x@Wb.T + bb + oseq@(4*Wup).T
// 8 waves (2M x 4N); wave owns 128x64 via rowmap: mi<4 -> rows wm*64+mi*16 (tile half0),
// mi>=4 -> 128+wm*64+(mi-4)*16 (half1); same split for B cols. Phases q0..q3 consume
// (Ah0,Bh0),(Bh1),(Ah1),() and stage tile T+2 into the region just freed.
// LDS swizzle: 16B slot ^= (row&7), applied on the global source (gld_lds dest linear)
// and identically on ds_read addresses.
__global__ __launch_bounds__(512, 2) void k_gemm2(const u16* __restrict__ xb,
                                                  const u16* __restrict__ wbb,
                                                  const u16* __restrict__ oseq,
                                                  const u16* __restrict__ wupb,
                                                  const float* __restrict__ bb,
                                                  float* __restrict__ out) {
  extern __shared__ u16 sm[];  // 2 bufs x (A 16384 + B 16384) elems = 128 KiB
  int bid = blockIdx.x;
  int swz = (bid & 7) * 128 + (bid >> 3);  // 1024 % 8 == 0 -> bijective
  int mt = swz >> 2, nt = swz & 3;
  int m0 = mt * 256, n0 = nt * 256;
  int tid = threadIdx.x;
  int l = tid & 63, w = tid >> 6;
  int wm = w >> 2, wn = w & 3;
  int g = l >> 4, l15 = l & 15, l7 = l & 7, l3 = l >> 3;
  int offk0 = (g ^ l7) * 8;          // elems; kk=0 slot swizzle
  int offk1 = ((g + 4) ^ l7) * 8;    // kk=1
  int ar[8], brr[4], rAnl[8], rBl[4];
#pragma unroll
  for (int mi = 0; mi < 8; ++mi) {
    int rm = (mi < 4) ? (wm * 64 + mi * 16) : (128 + wm * 64 + (mi - 4) * 16);
    rAnl[mi] = rm;
    ar[mi] = (rm + l15) * 64;
  }
#pragma unroll
  for (int nj = 0; nj < 4; ++nj) {
    int rn = (nj < 2) ? (wn * 32 + nj * 16) : (128 + wn * 32 + (nj - 2) * 16);
    rBl[nj] = rn + l15;
    brr[nj] = 16384 + (rn + l15) * 64;
  }
  int slotg = l7 ^ l3;  // inverse swizzle on the global source
  const u16* pA[4];
  const u16* pB[4];
#pragma unroll
  for (int j = 0; j < 4; ++j) {
    pA[j] = xb  + (size_t)(m0 + (j * 8 + w) * 8 + l3) * 1024 + slotg * 8;
    pB[j] = wbb + (size_t)(n0 + (j * 8 + w) * 8 + l3) * 1024 + slotg * 8;
  }
  // prologue: tile0 -> buf0, tile1 -> buf1 (issue order matters for vmcnt)
#pragma unroll
  for (int j = 0; j < 4; ++j) async16(sm + (j * 8 + w) * 512, pA[j]);
#pragma unroll
  for (int j = 0; j < 4; ++j) async16(sm + 16384 + (j * 8 + w) * 512, pB[j]);
#pragma unroll
  for (int j = 0; j < 4; ++j) async16(sm + 32768 + (j * 8 + w) * 512, pA[j] + 64);
#pragma unroll
  for (int j = 0; j < 4; ++j) async16(sm + 32768 + 16384 + (j * 8 + w) * 512, pB[j] + 64);
#pragma unroll
  for (int j = 0; j < 4; ++j) { pA[j] += 128; pB[j] += 128; }
  f32x4 acc[8][4] = {};
  asm volatile("s_waitcnt vmcnt(8)" ::: "memory");  // tile0 landed (tile1 in flight)
  __builtin_amdgcn_sched_barrier(0);
  BARR;
  short8 af[4][2], bq[4][2];
  for (int T = 0; T < 16; ++T) {
    int sb = (T & 1) * 32768;
    const u16* SA = sm + sb;
    u16* stg = sm + sb;
    // ---- q0: read A half0 + B half0; stage next A-h0,B-h0; MFMA (mh0 x nh0)
#pragma unroll
    for (int mi = 0; mi < 4; ++mi) {
      af[mi][0] = *(const short8*)(SA + ar[mi] + offk0);
      af[mi][1] = *(const short8*)(SA + ar[mi] + offk1);
    }
#pragma unroll
    for (int nj = 0; nj < 2; ++nj) {
      bq[nj][0] = *(const short8*)(SA + brr[nj] + offk0);
      bq[nj][1] = *(const short8*)(SA + brr[nj] + offk1);
    }
    LGKM0;
    BARR;
    if (T < 14) {
      async16(stg + (0 * 8 + w) * 512, pA[0]);
      async16(stg + (1 * 8 + w) * 512, pA[1]);
      async16(stg + 16384 + (0 * 8 + w) * 512, pB[0]);
      async16(stg + 16384 + (1 * 8 + w) * 512, pB[1]);
    }
    __builtin_amdgcn_sched_barrier(0);
    __builtin_amdgcn_s_setprio(1);
#pragma unroll
    for (int mi = 0; mi < 4; ++mi)
#pragma unroll
      for (int nj = 0; nj < 2; ++nj) {
        acc[mi][nj] = MFMA16(af[mi][0], bq[nj][0], acc[mi][nj]);
        acc[mi][nj] = MFMA16(af[mi][1], bq[nj][1], acc[mi][nj]);
      }
    __builtin_amdgcn_s_setprio(0);
    // ---- q1: read B half1; stage next B-h1; MFMA (mh0 x nh1)
#pragma unroll
    for (int nj = 2; nj < 4; ++nj) {
      bq[nj][0] = *(const short8*)(SA + brr[nj] + offk0);
      bq[nj][1] = *(const short8*)(SA + brr[nj] + offk1);
    }
    LGKM0;
    BARR;
    if (T < 14) {
      async16(stg + 16384 + (2 * 8 + w) * 512, pB[2]);
      async16(stg + 16384 + (3 * 8 + w) * 512, pB[3]);
    }
    __builtin_amdgcn_sched_barrier(0);
    __builtin_amdgcn_s_setprio(1);
#pragma unroll
    for (int mi = 0; mi < 4; ++mi)
#pragma unroll
      for (int nj = 2; nj < 4; ++nj) {
        acc[mi][nj] = MFMA16(af[mi][0], bq[nj][0], acc[mi][nj]);
        acc[mi][nj] = MFMA16(af[mi][1], bq[nj][1], acc[mi][nj]);
      }
    __builtin_amdgcn_s_setprio(0);
    // ---- q2: read A half1; stage next A-h1; MFMA (mh1 x nh0)
#pragma unroll
    for (int mi = 0; mi < 4; ++mi) {
      af[mi][0] = *(const short8*)(SA + ar[4 + mi] + offk0);
      af[mi][1] = *(const short8*)(SA + ar[4 + mi] + offk1);
    }
    LGKM0;
    BARR;
    if (T < 14) {
      async16(stg + (2 * 8 + w) * 512, pA[2]);
      async16(stg + (3 * 8 + w) * 512, pA[3]);
    }
    __builtin_amdgcn_sched_barrier(0);
    __builtin_amdgcn_s_setprio(1);
#pragma unroll
    for (int mi = 0; mi < 4; ++mi)
#pragma unroll
      for (int nj = 0; nj < 2; ++nj) {
        acc[4 + mi][nj] = MFMA16(af[mi][0], bq[nj][0], acc[4 + mi][nj]);
        acc[4 + mi][nj] = MFMA16(af[mi][1], bq[nj][1], acc[4 + mi][nj]);
      }
    __builtin_amdgcn_s_setprio(0);
    // ---- q3: gate next tile (counted vmcnt, never 0 mid-loop); MFMA (mh1 x nh1)
    if (T < 14) {
      asm volatile("s_waitcnt vmcnt(8)" ::: "memory");
    } else {
      asm volatile("s_waitcnt vmcnt(0)" ::: "memory");
    }
    __builtin_amdgcn_sched_barrier(0);
    BARR;
    __builtin_amdgcn_s_setprio(1);
#pragma unroll
    for (int mi = 0; mi < 4; ++mi)
#pragma unroll
      for (int nj = 2; nj < 4; ++nj) {
        acc[4 + mi][nj] = MFMA16(af[mi][0], bq[nj][0], acc[4 + mi][nj]);
        acc[4 + mi][nj] = MFMA16(af[mi][1], bq[nj][1], acc[4 + mi][nj]);
      }
    __builtin_amdgcn_s_setprio(0);
#pragma unroll
    for (int j = 0; j < 4; ++j) { pA[j] += 64; pB[j] += 64; }
  }
  // ---- epilogue: delta (oseq @ (4*Wup).T, K=32) + bias + store
  short8 aeq[8], beq[4];
#pragma unroll
  for (int mi = 0; mi < 8; ++mi)
    aeq[mi] = *(const short8*)(oseq + (size_t)(m0 + rAnl[mi] + l15) * 32 + g * 8);
#pragma unroll
  for (int nj = 0; nj < 4; ++nj)
    beq[nj] = *(const short8*)(wupb + (size_t)(n0 + rBl[nj]) * 32 + g * 8);
#pragma unroll
  for (int mi = 0; mi < 8; ++mi)
#pragma unroll
    for (int nj = 0; nj < 4; ++nj)
      acc[mi][nj] = MFMA16(aeq[mi], beq[nj], acc[mi][nj]);
  float bias[4];
#pragma unroll
  for (int nj = 0; nj < 4; ++nj) bias[nj] = bb[n0 + rBl[nj]];
#pragma unroll
  for (int mi = 0; mi < 8; ++mi)
#pragma unroll
    for (int nj = 0; nj < 4; ++nj)
#pragma unroll
      for (int r = 0; r < 4; ++r)
        out[(size_t)(m0 + rAnl[mi] + g * 4 + r) * 1024 + n0 + rBl[nj]] =
            acc[mi][nj][r] + bias[nj];
}

extern "C" void kernel_launch(void* const* d_in, const int* in_sizes, int n_in,
                              void* d_out, int out_size, void* d_ws, size_t ws_size,
                              hipStream_t stream) {
  const float* x     = (const float*)d_in[0];
  const float* Wb    = (const float*)d_in[1];
  const float* bb    = (const float*)d_in[2];
  const float* Wdown = (const float*)d_in[3];
  const float* Wup   = (const float*)d_in[4];
  const float* A_log = (const float*)d_in[5];
  const float* Dp    = (const float*)d_in[6];
  const float* Wxp   = (const float*)d_in[7];
  const float* bxp   = (const float*)d_in[8];
  const float* Wout  = (const float*)d_in[9];
  const float* bout  = (const float*)d_in[10];

  char* ws = (char*)d_ws;
  u16*   xb     = (u16*)(ws);                      // 134217728 B
  u16*   wbb    = (u16*)(ws + 134217728);          // 2097152 B
  u16*   wdownb = (u16*)(ws + 136314880);          // 65536 B
  u16*   wupb   = (u16*)(ws + 136380416);          // 65536 B
  float* red    = (float*)(ws + 136445952);        // 8388608 B
  u16*   oseq   = (u16*)(ws + 144834560);          // 4194304 B
  float* out = (float*)d_out;

  hipFuncSetAttribute((const void*)k_gemm2,
                      hipFuncAttributeMaxDynamicSharedMemorySize, 131072);

  hipLaunchKernelGGL(k_conv_w, dim3(512), dim3(256), 0, stream, Wb, Wdown, Wup, wbb, wdownb, wupb);
  hipLaunchKernelGGL(k_prep, dim3(1024), dim3(256), 0, stream, x, wdownb, xb, red);
  hipLaunchKernelGGL(k_ssm, dim3(1024), dim3(256), 0, stream, red, oseq, A_log, Dp, Wxp, bxp, Wout, bout);
  hipLaunchKernelGGL(k_gemm2, dim3(1024), dim3(512), 131072, stream, xb, wbb, oseq, wupb, bb, out);
}